// Round 1
// baseline (1973.400 us; speedup 1.0000x reference)
//
#include <hip/hip_runtime.h>

// LightGCN-style propagation:
//   out = (f + A f + A (A f)) / 3,  where (A x)[i] = sum_{e: dst[e]==i} w[e] * x[src[e]]
// N=100000 nodes, E=1600000 edges, D=48 features, fp32.

static constexpr int D = 48;
static constexpr int V = D / 4;  // 12 float4 per node row

__global__ void hc_scatter(const float* __restrict__ x,
                           const float* __restrict__ w,
                           const int* __restrict__ src,
                           const int* __restrict__ dst,
                           float* __restrict__ out,
                           int E) {
    long long tid = (long long)blockIdx.x * blockDim.x + threadIdx.x;
    long long total = (long long)E * V;
    if (tid >= total) return;
    int e = (int)(tid / V);
    int c = (int)(tid % V);
    int s = src[e];
    int d = dst[e];
    float ww = w[e];
    float4 v = reinterpret_cast<const float4*>(x)[(long long)s * V + c];
    float* o = out + ((long long)d * D + c * 4);
    atomicAdd(o + 0, ww * v.x);
    atomicAdd(o + 1, ww * v.y);
    atomicAdd(o + 2, ww * v.z);
    atomicAdd(o + 3, ww * v.w);
}

__global__ void hc_combine(const float* __restrict__ f,
                           const float* __restrict__ x1,
                           const float* __restrict__ x2,
                           float* __restrict__ out,
                           int n4) {
    int i = blockIdx.x * blockDim.x + threadIdx.x;
    if (i >= n4) return;
    const float4 a = reinterpret_cast<const float4*>(f)[i];
    const float4 b = reinterpret_cast<const float4*>(x1)[i];
    const float4 c = reinterpret_cast<const float4*>(x2)[i];
    constexpr float s = 1.0f / 3.0f;
    float4 r;
    r.x = (a.x + b.x + c.x) * s;
    r.y = (a.y + b.y + c.y) * s;
    r.z = (a.z + b.z + c.z) * s;
    r.w = (a.w + b.w + c.w) * s;
    reinterpret_cast<float4*>(out)[i] = r;
}

extern "C" void kernel_launch(void* const* d_in, const int* in_sizes, int n_in,
                              void* d_out, int out_size, void* d_ws, size_t ws_size,
                              hipStream_t stream) {
    const float* features = (const float*)d_in[0];
    const float* ew       = (const float*)d_in[1];
    const int*   ei       = (const int*)d_in[2];

    const int E = in_sizes[1];          // 1,600,000
    const int N = in_sizes[0] / D;      // 100,000

    const int* src = ei;        // row 0 of [2, E]
    const int* dst = ei + E;    // row 1 of [2, E]

    float* x1 = (float*)d_ws;
    float* x2 = x1 + (size_t)N * D;

    // Zero accumulation buffers every call (ws is poisoned once, never re-poisoned).
    hipMemsetAsync(d_ws, 0, 2 * (size_t)N * D * sizeof(float), stream);

    const int blk = 256;
    long long total = (long long)E * V;
    int grid = (int)((total + blk - 1) / blk);

    hc_scatter<<<grid, blk, 0, stream>>>(features, ew, src, dst, x1, E);
    hc_scatter<<<grid, blk, 0, stream>>>(x1, ew, src, dst, x2, E);

    int n4 = N * D / 4;
    hc_combine<<<(n4 + blk - 1) / blk, blk, 0, stream>>>(features, x1, x2, (float*)d_out, n4);
}

// Round 2
// 538.230 us; speedup vs baseline: 3.6665x; 3.6665x over previous
//
#include <hip/hip_runtime.h>

// LightGCN propagation: out = (f + A f + A (A f)) / 3
//   (A x)[i] = sum_{e: dst[e]==i} w[e] * x[src[e]]
// N=100000, E=1600000, D=48, fp32.
//
// Strategy: build dst-sorted CSR on device (histogram -> scan -> fill),
// then SpMM as gather (no float atomics). Pass 2 fuses the final combine.

static constexpr int D = 48;

// ---------- CSR build ----------

__global__ void hc_hist(const int* __restrict__ dst, int* __restrict__ cnt, int E) {
    for (int e = blockIdx.x * blockDim.x + threadIdx.x; e < E;
         e += gridDim.x * blockDim.x)
        atomicAdd(&cnt[dst[e]], 1);
}

// Single-block exclusive scan over N counts.
// in/out: cnt[] (counts -> running start positions, i.e. fill cursor)
// out:    row_ptr[0..N] (CSR row pointers)
__global__ __launch_bounds__(1024) void hc_scan(int* __restrict__ cnt,
                                                int* __restrict__ row_ptr, int N) {
    __shared__ int sdata[1024];
    const int t = threadIdx.x;
    const int chunk = (N + 1023) >> 10;
    const int lo = t * chunk;
    const int hi = min(lo + chunk, N);

    int s = 0;
    for (int i = lo; i < hi; ++i) s += cnt[i];
    sdata[t] = s;
    __syncthreads();
    // Hillis-Steele inclusive scan
    for (int off = 1; off < 1024; off <<= 1) {
        int v = (t >= off) ? sdata[t - off] : 0;
        __syncthreads();
        sdata[t] += v;
        __syncthreads();
    }
    int run = sdata[t] - s;  // exclusive prefix of this thread's chunk
    if (t == 1023) row_ptr[N] = sdata[1023];
    for (int i = lo; i < hi; ++i) {
        int c = cnt[i];
        row_ptr[i] = run;
        cnt[i] = run;  // becomes the fill cursor
        run += c;
    }
}

__global__ void hc_fill(const int* __restrict__ src, const int* __restrict__ dst,
                        const float* __restrict__ w, int* __restrict__ cursor,
                        int* __restrict__ col, float* __restrict__ wsort, int E) {
    for (int e = blockIdx.x * blockDim.x + threadIdx.x; e < E;
         e += gridDim.x * blockDim.x) {
        int d = dst[e];
        int pos = atomicAdd(&cursor[d], 1);
        col[pos] = src[e];
        wsort[pos] = w[e];
    }
}

// ---------- gather SpMM ----------
// One wave (64 lanes) per destination node: 4 edge-slots x 16 feature-lanes,
// each lane owns 3 consecutive features. Register accumulate, shuffle-reduce
// across edge-slots, single write per output element.
template <bool FINAL>
__global__ void hc_gather(const float* __restrict__ xin,
                          const int* __restrict__ row_ptr,
                          const int* __restrict__ col,
                          const float* __restrict__ wsort,
                          const float* __restrict__ f,
                          const float* __restrict__ x1,
                          float* __restrict__ out, int N) {
    const int lane = threadIdx.x & 63;
    const int node = blockIdx.x * (blockDim.x >> 6) + (threadIdx.x >> 6);
    if (node >= N) return;
    const int eslot = lane >> 4;  // 0..3
    const int fl = lane & 15;     // features [fl*3, fl*3+3)

    const int start = row_ptr[node];
    const int end = row_ptr[node + 1];

    float a0 = 0.f, a1 = 0.f, a2 = 0.f;
    for (int eb = start; eb < end; eb += 4) {
        int e = eb + eslot;
        if (e < end) {
            float w = wsort[e];
            const float* xr = xin + (long long)col[e] * D + fl * 3;
            a0 += w * xr[0];
            a1 += w * xr[1];
            a2 += w * xr[2];
        }
    }
    a0 += __shfl_xor(a0, 16); a1 += __shfl_xor(a1, 16); a2 += __shfl_xor(a2, 16);
    a0 += __shfl_xor(a0, 32); a1 += __shfl_xor(a1, 32); a2 += __shfl_xor(a2, 32);

    if (eslot == 0) {
        const long long b = (long long)node * D + fl * 3;
        if (FINAL) {
            constexpr float s = 1.0f / 3.0f;
            out[b + 0] = (f[b + 0] + x1[b + 0] + a0) * s;
            out[b + 1] = (f[b + 1] + x1[b + 1] + a1) * s;
            out[b + 2] = (f[b + 2] + x1[b + 2] + a2) * s;
        } else {
            out[b + 0] = a0;
            out[b + 1] = a1;
            out[b + 2] = a2;
        }
    }
}

extern "C" void kernel_launch(void* const* d_in, const int* in_sizes, int n_in,
                              void* d_out, int out_size, void* d_ws, size_t ws_size,
                              hipStream_t stream) {
    const float* features = (const float*)d_in[0];
    const float* ew       = (const float*)d_in[1];
    const int*   ei       = (const int*)d_in[2];

    const int E = in_sizes[1];      // 1,600,000
    const int N = in_sizes[0] / D;  // 100,000

    const int* src = ei;
    const int* dst = ei + E;

    // Workspace layout (~33 MB)
    float* x1      = (float*)d_ws;                    // N*D
    int*   row_ptr = (int*)(x1 + (size_t)N * D);      // N+1
    int*   cursor  = row_ptr + (N + 1);               // N (counts -> cursor)
    int*   col     = cursor + N;                      // E
    float* wsort   = (float*)(col + E);               // E

    hipMemsetAsync(cursor, 0, (size_t)N * sizeof(int), stream);

    const int blk = 256;
    const int gsE = 2048;  // grid-stride blocks for edge-parallel kernels

    hc_hist<<<gsE, blk, 0, stream>>>(dst, cursor, E);
    hc_scan<<<1, 1024, 0, stream>>>(cursor, row_ptr, N);
    hc_fill<<<gsE, blk, 0, stream>>>(src, dst, ew, cursor, col, wsort, E);

    const int nodes_per_block = blk / 64;  // 4
    const int ggrid = (N + nodes_per_block - 1) / nodes_per_block;

    hc_gather<false><<<ggrid, blk, 0, stream>>>(features, row_ptr, col, wsort,
                                                nullptr, nullptr, x1, N);
    hc_gather<true><<<ggrid, blk, 0, stream>>>(x1, row_ptr, col, wsort,
                                               features, x1, (float*)d_out, N);
}

// Round 3
// 341.895 us; speedup vs baseline: 5.7719x; 1.5743x over previous
//
#include <hip/hip_runtime.h>

// LightGCN propagation: out = (f + A f + A (A f)) / 3
//   (A x)[i] = sum_{e: dst[e]==i} w[e] * x[src[e]]
// N=100000, E=1600000, D=48, fp32.
//
// CSR build (histogram -> two-level scan -> fill, edges packed as int2),
// then SpMM as gather (no float atomics). Pass 2 fuses the final combine.

static constexpr int D = 48;
static constexpr int SCAN_T = 256;
static constexpr int SCAN_I = 4;
static constexpr int SCAN_CHUNK = SCAN_T * SCAN_I;  // 1024

// ---------- CSR build ----------

__global__ void hc_hist(const int* __restrict__ dst, int* __restrict__ cnt, int E) {
    for (int e = blockIdx.x * blockDim.x + threadIdx.x; e < E;
         e += gridDim.x * blockDim.x)
        atomicAdd(&cnt[dst[e]], 1);
}

// Stage A: per-chunk sums.
__global__ __launch_bounds__(SCAN_T) void hc_blocksum(const int* __restrict__ cnt,
                                                      int* __restrict__ blkSum, int N) {
    __shared__ int sm[SCAN_T];
    const int t = threadIdx.x;
    const int base = blockIdx.x * SCAN_CHUNK + t * SCAN_I;
    int s = 0;
#pragma unroll
    for (int k = 0; k < SCAN_I; ++k) {
        int i = base + k;
        if (i < N) s += cnt[i];
    }
    sm[t] = s;
    __syncthreads();
    for (int off = SCAN_T / 2; off > 0; off >>= 1) {
        if (t < off) sm[t] += sm[t + off];
        __syncthreads();
    }
    if (t == 0) blkSum[blockIdx.x] = sm[0];
}

// Stage B: scan the (<=128) block sums; exclusive offsets in-place, total -> row_ptr[N].
__global__ __launch_bounds__(128) void hc_scanblk(int* __restrict__ blkSum,
                                                  int* __restrict__ row_ptr,
                                                  int nblk, int N) {
    __shared__ int sm[128];
    const int t = threadIdx.x;
    int v = (t < nblk) ? blkSum[t] : 0;
    sm[t] = v;
    __syncthreads();
    for (int off = 1; off < 128; off <<= 1) {
        int u = (t >= off) ? sm[t - off] : 0;
        __syncthreads();
        sm[t] += u;
        __syncthreads();
    }
    if (t < nblk) blkSum[t] = sm[t] - v;  // exclusive
    if (t == 127) row_ptr[N] = sm[127];
}

// Stage C: local exclusive scan + block offset -> row_ptr / cursor (in-place over cnt).
__global__ __launch_bounds__(SCAN_T) void hc_blockscan(int* __restrict__ cnt,
                                                       const int* __restrict__ blkOff,
                                                       int* __restrict__ row_ptr, int N) {
    __shared__ int sm[SCAN_T];
    const int t = threadIdx.x;
    const int base = blockIdx.x * SCAN_CHUNK + t * SCAN_I;
    int c[SCAN_I];
    int s = 0;
#pragma unroll
    for (int k = 0; k < SCAN_I; ++k) {
        int i = base + k;
        c[k] = (i < N) ? cnt[i] : 0;
        s += c[k];
    }
    sm[t] = s;
    __syncthreads();
    for (int off = 1; off < SCAN_T; off <<= 1) {
        int u = (t >= off) ? sm[t - off] : 0;
        __syncthreads();
        sm[t] += u;
        __syncthreads();
    }
    int run = blkOff[blockIdx.x] + sm[t] - s;
#pragma unroll
    for (int k = 0; k < SCAN_I; ++k) {
        int i = base + k;
        if (i < N) {
            row_ptr[i] = run;
            cnt[i] = run;  // fill cursor
            run += c[k];
        }
    }
}

__global__ void hc_fill(const int* __restrict__ src, const int* __restrict__ dst,
                        const float* __restrict__ w, int* __restrict__ cursor,
                        int2* __restrict__ cw, int E) {
    for (int e = blockIdx.x * blockDim.x + threadIdx.x; e < E;
         e += gridDim.x * blockDim.x) {
        int d = dst[e];
        int pos = atomicAdd(&cursor[d], 1);
        cw[pos] = make_int2(src[e], __float_as_int(w[e]));
    }
}

// ---------- gather SpMM ----------
// One wave per destination node: 4 edge-slots x 16 feature-lanes, 3 floats/lane.
template <bool FINAL>
__global__ void hc_gather(const float* __restrict__ xin,
                          const int* __restrict__ row_ptr,
                          const int2* __restrict__ cw,
                          const float* __restrict__ f,
                          const float* __restrict__ x1,
                          float* __restrict__ out, int N) {
    const int lane = threadIdx.x & 63;
    const int node = blockIdx.x * (blockDim.x >> 6) + (threadIdx.x >> 6);
    if (node >= N) return;
    const int eslot = lane >> 4;  // 0..3
    const int fl = lane & 15;     // features [fl*3, fl*3+3)

    const int start = row_ptr[node];
    const int end = row_ptr[node + 1];

    float a0 = 0.f, a1 = 0.f, a2 = 0.f;
    for (int eb = start; eb < end; eb += 4) {
        int e = eb + eslot;
        if (e < end) {
            int2 p = cw[e];
            float w = __int_as_float(p.y);
            const float* xr = xin + (long long)p.x * D + fl * 3;
            a0 += w * xr[0];
            a1 += w * xr[1];
            a2 += w * xr[2];
        }
    }
    a0 += __shfl_xor(a0, 16); a1 += __shfl_xor(a1, 16); a2 += __shfl_xor(a2, 16);
    a0 += __shfl_xor(a0, 32); a1 += __shfl_xor(a1, 32); a2 += __shfl_xor(a2, 32);

    if (eslot == 0) {
        const long long b = (long long)node * D + fl * 3;
        if (FINAL) {
            constexpr float s = 1.0f / 3.0f;
            out[b + 0] = (f[b + 0] + x1[b + 0] + a0) * s;
            out[b + 1] = (f[b + 1] + x1[b + 1] + a1) * s;
            out[b + 2] = (f[b + 2] + x1[b + 2] + a2) * s;
        } else {
            out[b + 0] = a0;
            out[b + 1] = a1;
            out[b + 2] = a2;
        }
    }
}

extern "C" void kernel_launch(void* const* d_in, const int* in_sizes, int n_in,
                              void* d_out, int out_size, void* d_ws, size_t ws_size,
                              hipStream_t stream) {
    const float* features = (const float*)d_in[0];
    const float* ew       = (const float*)d_in[1];
    const int*   ei       = (const int*)d_in[2];

    const int E = in_sizes[1];      // 1,600,000
    const int N = in_sizes[0] / D;  // 100,000

    const int* src = ei;
    const int* dst = ei + E;

    // Workspace layout (~33 MB)
    float* x1      = (float*)d_ws;                 // N*D
    int*   row_ptr = (int*)(x1 + (size_t)N * D);   // N+1
    int*   cursor  = row_ptr + (N + 1);            // N (counts -> cursor)
    int*   blkSum  = cursor + N;                   // <=128
    uintptr_t cw_addr = ((uintptr_t)(blkSum + 128) + 7) & ~(uintptr_t)7;
    int2*  cw      = (int2*)cw_addr;               // E (col, weight)

    hipMemsetAsync(cursor, 0, (size_t)N * sizeof(int), stream);

    const int blk = 256;
    const int gsE = 2048;
    const int nblk = (N + SCAN_CHUNK - 1) / SCAN_CHUNK;  // 98 (<=128)

    hc_hist<<<gsE, blk, 0, stream>>>(dst, cursor, E);
    hc_blocksum<<<nblk, SCAN_T, 0, stream>>>(cursor, blkSum, N);
    hc_scanblk<<<1, 128, 0, stream>>>(blkSum, row_ptr, nblk, N);
    hc_blockscan<<<nblk, SCAN_T, 0, stream>>>(cursor, blkSum, row_ptr, N);
    hc_fill<<<gsE, blk, 0, stream>>>(src, dst, ew, cursor, cw, E);

    const int nodes_per_block = blk / 64;  // 4
    const int ggrid = (N + nodes_per_block - 1) / nodes_per_block;

    hc_gather<false><<<ggrid, blk, 0, stream>>>(features, row_ptr, cw, nullptr,
                                                nullptr, x1, N);
    hc_gather<true><<<ggrid, blk, 0, stream>>>(x1, row_ptr, cw, features, x1,
                                               (float*)d_out, N);
}

// Round 4
// 285.884 us; speedup vs baseline: 6.9028x; 1.1959x over previous
//
#include <hip/hip_runtime.h>

// LightGCN propagation: out = (f + A f + A (A f)) / 3
//   (A x)[i] = sum_{e: dst[e]==i} w[e] * x[src[e]]
// N=100000, E=1600000, D=48, fp32.
//
// CSR build: histogram -> two-level scan -> XCD-partitioned fill (each of 8
// teams reads all edges, places only its dst-range; keeps every cw cache line
// owned by ONE XCD's L2 -> no cross-XCD write amplification).
// SpMM as gather; pass 2 fuses the final combine.

static constexpr int D = 48;
static constexpr int SCAN_T = 256;
static constexpr int SCAN_I = 4;
static constexpr int SCAN_CHUNK = SCAN_T * SCAN_I;  // 1024
static constexpr int NTEAM = 8;                     // = # XCDs

// ---------- CSR build ----------

__global__ void hc_hist(const int* __restrict__ dst, int* __restrict__ cnt, int E) {
    for (int e = blockIdx.x * blockDim.x + threadIdx.x; e < E;
         e += gridDim.x * blockDim.x)
        atomicAdd(&cnt[dst[e]], 1);
}

__global__ __launch_bounds__(SCAN_T) void hc_blocksum(const int* __restrict__ cnt,
                                                      int* __restrict__ blkSum, int N) {
    __shared__ int sm[SCAN_T];
    const int t = threadIdx.x;
    const int base = blockIdx.x * SCAN_CHUNK + t * SCAN_I;
    int s = 0;
#pragma unroll
    for (int k = 0; k < SCAN_I; ++k) {
        int i = base + k;
        if (i < N) s += cnt[i];
    }
    sm[t] = s;
    __syncthreads();
    for (int off = SCAN_T / 2; off > 0; off >>= 1) {
        if (t < off) sm[t] += sm[t + off];
        __syncthreads();
    }
    if (t == 0) blkSum[blockIdx.x] = sm[0];
}

__global__ __launch_bounds__(128) void hc_scanblk(int* __restrict__ blkSum,
                                                  int* __restrict__ row_ptr,
                                                  int nblk, int N) {
    __shared__ int sm[128];
    const int t = threadIdx.x;
    int v = (t < nblk) ? blkSum[t] : 0;
    sm[t] = v;
    __syncthreads();
    for (int off = 1; off < 128; off <<= 1) {
        int u = (t >= off) ? sm[t - off] : 0;
        __syncthreads();
        sm[t] += u;
        __syncthreads();
    }
    if (t < nblk) blkSum[t] = sm[t] - v;  // exclusive
    if (t == 127) row_ptr[N] = sm[127];
}

__global__ __launch_bounds__(SCAN_T) void hc_blockscan(int* __restrict__ cnt,
                                                       const int* __restrict__ blkOff,
                                                       int* __restrict__ row_ptr, int N) {
    __shared__ int sm[SCAN_T];
    const int t = threadIdx.x;
    const int base = blockIdx.x * SCAN_CHUNK + t * SCAN_I;
    int c[SCAN_I];
    int s = 0;
#pragma unroll
    for (int k = 0; k < SCAN_I; ++k) {
        int i = base + k;
        c[k] = (i < N) ? cnt[i] : 0;
        s += c[k];
    }
    sm[t] = s;
    __syncthreads();
    for (int off = 1; off < SCAN_T; off <<= 1) {
        int u = (t >= off) ? sm[t - off] : 0;
        __syncthreads();
        sm[t] += u;
        __syncthreads();
    }
    int run = blkOff[blockIdx.x] + sm[t] - s;
#pragma unroll
    for (int k = 0; k < SCAN_I; ++k) {
        int i = base + k;
        if (i < N) {
            row_ptr[i] = run;
            cnt[i] = run;  // fill cursor
            run += c[k];
        }
    }
}

// XCD-partitioned fill: team = blockIdx&7 (maps to one XCD under the observed
// round-robin blockIdx->XCD assignment). Each team streams ALL edges, keeps
// only dst in its node range -> all stores to a given cw line come from one
// XCD's L2 -> line assembled once, written back once.
__global__ void hc_fill_team(const int* __restrict__ src, const int* __restrict__ dst,
                             const float* __restrict__ w, int* __restrict__ cursor,
                             int2* __restrict__ cw, int E, int npt) {
    const int team = blockIdx.x & (NTEAM - 1);
    const int sub = blockIdx.x >> 3;
    const int nsub = gridDim.x >> 3;
    const int lo = team * npt;
    const int hi = lo + npt;
    for (int e = sub * blockDim.x + threadIdx.x; e < E; e += nsub * blockDim.x) {
        int d = dst[e];
        if (d >= lo && d < hi) {
            int pos = atomicAdd(&cursor[d], 1);
            cw[pos] = make_int2(src[e], __float_as_int(w[e]));
        }
    }
}

// ---------- gather SpMM ----------
// One wave per destination node: 4 edge-slots x 16 feature-lanes, 3 floats/lane.
template <bool FINAL>
__global__ void hc_gather(const float* __restrict__ xin,
                          const int* __restrict__ row_ptr,
                          const int2* __restrict__ cw,
                          const float* __restrict__ f,
                          const float* __restrict__ x1,
                          float* __restrict__ out, int N) {
    const int lane = threadIdx.x & 63;
    const int node = blockIdx.x * (blockDim.x >> 6) + (threadIdx.x >> 6);
    if (node >= N) return;
    const int eslot = lane >> 4;  // 0..3
    const int fl = lane & 15;     // features [fl*3, fl*3+3)

    const int start = row_ptr[node];
    const int end = row_ptr[node + 1];

    float a0 = 0.f, a1 = 0.f, a2 = 0.f;
    for (int eb = start; eb < end; eb += 4) {
        int e = eb + eslot;
        if (e < end) {
            int2 p = cw[e];
            float w = __int_as_float(p.y);
            const float* xr = xin + (long long)p.x * D + fl * 3;
            a0 += w * xr[0];
            a1 += w * xr[1];
            a2 += w * xr[2];
        }
    }
    a0 += __shfl_xor(a0, 16); a1 += __shfl_xor(a1, 16); a2 += __shfl_xor(a2, 16);
    a0 += __shfl_xor(a0, 32); a1 += __shfl_xor(a1, 32); a2 += __shfl_xor(a2, 32);

    if (eslot == 0) {
        const long long b = (long long)node * D + fl * 3;
        if (FINAL) {
            constexpr float s = 1.0f / 3.0f;
            out[b + 0] = (f[b + 0] + x1[b + 0] + a0) * s;
            out[b + 1] = (f[b + 1] + x1[b + 1] + a1) * s;
            out[b + 2] = (f[b + 2] + x1[b + 2] + a2) * s;
        } else {
            out[b + 0] = a0;
            out[b + 1] = a1;
            out[b + 2] = a2;
        }
    }
}

extern "C" void kernel_launch(void* const* d_in, const int* in_sizes, int n_in,
                              void* d_out, int out_size, void* d_ws, size_t ws_size,
                              hipStream_t stream) {
    const float* features = (const float*)d_in[0];
    const float* ew       = (const float*)d_in[1];
    const int*   ei       = (const int*)d_in[2];

    const int E = in_sizes[1];      // 1,600,000
    const int N = in_sizes[0] / D;  // 100,000

    const int* src = ei;
    const int* dst = ei + E;

    // Workspace layout (~33 MB)
    float* x1      = (float*)d_ws;                 // N*D
    int*   row_ptr = (int*)(x1 + (size_t)N * D);   // N+1
    int*   cursor  = row_ptr + (N + 1);            // N (counts -> cursor)
    int*   blkSum  = cursor + N;                   // <=128
    uintptr_t cw_addr = ((uintptr_t)(blkSum + 128) + 7) & ~(uintptr_t)7;
    int2*  cw      = (int2*)cw_addr;               // E (col, weight)

    hipMemsetAsync(cursor, 0, (size_t)N * sizeof(int), stream);

    const int blk = 256;
    const int gsE = 2048;
    const int nblk = (N + SCAN_CHUNK - 1) / SCAN_CHUNK;  // 98 (<=128)
    const int npt = (N + NTEAM - 1) / NTEAM;             // 12500 nodes per team

    hc_hist<<<gsE, blk, 0, stream>>>(dst, cursor, E);
    hc_blocksum<<<nblk, SCAN_T, 0, stream>>>(cursor, blkSum, N);
    hc_scanblk<<<1, 128, 0, stream>>>(blkSum, row_ptr, nblk, N);
    hc_blockscan<<<nblk, SCAN_T, 0, stream>>>(cursor, blkSum, row_ptr, N);
    hc_fill_team<<<NTEAM * 256, blk, 0, stream>>>(src, dst, ew, cursor, cw, E, npt);

    const int nodes_per_block = blk / 64;  // 4
    const int ggrid = (N + nodes_per_block - 1) / nodes_per_block;

    hc_gather<false><<<ggrid, blk, 0, stream>>>(features, row_ptr, cw, nullptr,
                                                nullptr, x1, N);
    hc_gather<true><<<ggrid, blk, 0, stream>>>(x1, row_ptr, cw, features, x1,
                                               (float*)d_out, N);
}